// Round 4
// baseline (188.914 us; speedup 1.0000x reference)
//
#include <hip/hip_runtime.h>
#include <cstddef>

// DCT-II matrix (float32 cast of numpy's float64 values)
static constexpr float D8[8][8] = {
  { 0.35355339059327373f, 0.35355339059327373f, 0.35355339059327373f, 0.35355339059327373f,
    0.35355339059327373f, 0.35355339059327373f, 0.35355339059327373f, 0.35355339059327373f},
  { 0.4903926402016152f,  0.4157348061512726f,  0.27778511650980114f, 0.09754516100806417f,
   -0.09754516100806417f,-0.27778511650980114f,-0.4157348061512726f, -0.4903926402016152f},
  { 0.46193976625564337f, 0.19134171618254492f,-0.19134171618254492f,-0.46193976625564337f,
   -0.46193976625564337f,-0.19134171618254492f, 0.19134171618254492f, 0.46193976625564337f},
  { 0.4157348061512726f, -0.09754516100806417f,-0.4903926402016152f, -0.27778511650980114f,
    0.27778511650980114f, 0.4903926402016152f,  0.09754516100806417f,-0.4157348061512726f},
  { 0.35355339059327373f,-0.35355339059327373f,-0.35355339059327373f, 0.35355339059327373f,
    0.35355339059327373f,-0.35355339059327373f,-0.35355339059327373f, 0.35355339059327373f},
  { 0.27778511650980114f,-0.4903926402016152f,  0.09754516100806417f, 0.4157348061512726f,
   -0.4157348061512726f, -0.09754516100806417f, 0.4903926402016152f, -0.27778511650980114f},
  { 0.19134171618254492f,-0.46193976625564337f, 0.46193976625564337f,-0.19134171618254492f,
   -0.19134171618254492f, 0.46193976625564337f,-0.46193976625564337f, 0.19134171618254492f},
  { 0.09754516100806417f,-0.27778511650980114f, 0.4157348061512726f, -0.4903926402016152f,
    0.4903926402016152f, -0.4157348061512726f,  0.27778511650980114f,-0.09754516100806417f},
};

// Quality-95 quant tables: q = clamp(floor((base*10+50)/100), 1, 255)
static constexpr float QLt[8][8] = {
  {2,1,1,2,2,4,5,6},
  {1,1,1,2,3,6,6,6},
  {1,1,2,2,4,6,7,6},
  {1,2,2,3,5,9,8,6},
  {2,2,4,6,7,11,10,8},
  {2,4,6,6,8,10,11,9},
  {5,6,8,9,10,12,12,10},
  {7,9,10,10,11,10,10,10},
};
static constexpr float QCt[8][8] = {
  {2,2,2,5,10,10,10,10},
  {2,2,3,7,10,10,10,10},
  {2,3,6,10,10,10,10,10},
  {5,7,10,10,10,10,10,10},
  {10,10,10,10,10,10,10,10},
  {10,10,10,10,10,10,10,10},
  {10,10,10,10,10,10,10,10},
  {10,10,10,10,10,10,10,10},
};

// Packed (q, RN(1/q)) tables, reciprocal folded at compile time (IEEE RN).
struct F2 { float q, r; };
struct QTab { F2 v[8][8]; };
static constexpr QTab mkq(const float (&b)[8][8]) {
  QTab t{};
  for (int i = 0; i < 8; ++i)
    for (int j = 0; j < 8; ++j) { t.v[i][j].q = b[i][j]; t.v[i][j].r = 1.0f / b[i][j]; }
  return t;
}
static constexpr QTab QLp = mkq(QLt);
static constexpr QTab QCp = mkq(QCt);

__device__ __forceinline__ void dct8(const float x[8], float u[8]) {
  #pragma unroll
  for (int k = 0; k < 8; ++k) {
    float a = D8[k][0] * x[0];
    #pragma unroll
    for (int j = 1; j < 8; ++j) a += D8[k][j] * x[j];
    u[k] = a;
  }
}
__device__ __forceinline__ void idct8(const float x[8], float u[8]) {
  #pragma unroll
  for (int j = 0; j < 8; ++j) {
    float a = x[0] * D8[0][j];
    #pragma unroll
    for (int m = 1; m < 8; ++m) a += x[m] * D8[m][j];
    u[j] = a;
  }
}

// Bit-exact floor(x / RN(1/255)): fast mul path; near-integer lanes (P~4e-4)
// resolve with the true IEEE division.
__device__ __forceinline__ float to255(float x) {
  const float c255 = (float)(1.0 / 255.0);
  float y  = x * 255.0f;
  float fl = floorf(y);
  float fr = y - fl;
  if (__builtin_expect(fr < 2e-4f || fr > 1.0f - 2e-4f, 0)) {
    fl = floorf(x / c255);
  }
  return fminf(fmaxf(fl, 0.0f), 255.0f);
}

// Bit-exact rintf(RN(u/q)): reciprocal-mul path; near-tie lanes (P~2e-3)
// re-do the true division (reproduces reference double-rounding).
__device__ __forceinline__ float quant_rt(float u, F2 qp) {
  float tq = u * qp.r;
  float n  = rintf(tq);
  float d  = fabsf(tq - n);
  if (__builtin_expect(d > 0.499f, 0)) {
    n = rintf(u / qp.q);
  }
  return n * qp.q;
}

// Wave-autonomous design: each wave64 owns a 16x32 pixel strip (2 JPEG
// macroblocks = 8 luma + 2 Cb + 2 Cr 8x8 blocks) end-to-end, using only its
// private LDS slice. NO __syncthreads anywhere — within-wave LDS write->read
// is ordered by the in-order DS pipe (wave64 lockstep). Waves drift apart and
// pipeline naturally (one wave's HBM loads overlap another's DCT math).
//
// Per-wave LDS slice (1792 floats = 7 KB), ping-pong regions A and B:
//   A: planes   Y[16][36]@0 | Cb[8][20]@576 | Cr[8][20]@736   (896 fl)
//      (reused) scratch2 [12][68]                              (816 fl)
//   B: scratch1 [12][68] -> then reconstructed planes (same layout as A)
// Block = 128 threads = 2 waves = 14336 B LDS -> 11 blocks/CU = 22 waves/CU.
__global__ __launch_bounds__(128) void jpeg_rt(const float* __restrict__ in,
                                               float* __restrict__ out)
{
  __shared__ __align__(16) float LDSB[2 * 1792];

  const int t   = threadIdx.x;
  const int w   = t >> 6;       // wave 0..1
  const int l   = t & 63;       // lane
  const int tx  = blockIdx.x;   // 0..7  (64-col band)
  const int ty  = blockIdx.y;   // 0..31 (16-row band)
  const int img = blockIdx.z;   // 0..31

  float* A = LDSB + w * 1792;         // planes / scratch2
  float* B = A + 896;                 // scratch1 / rec planes

  const int pr = l >> 3;        // 0..7: pixel rows 2pr,2pr+1
  const int pc = l & 7;         // 0..7: pixel cols 4pc..4pc+3 (in strip)
  const int colbase = tx*64 + w*32 + 4*pc;

  // ---------------- stage 1: load 2x4 patch, color convert -> A planes
  {
    const size_t r0 = (size_t)img * 512 + (size_t)(ty*16 + 2*pr);
    const float* rp0 = in + (r0*512 + colbase)*3;
    const float* rp1 = rp0 + 512*3;
    // issue all 6 loads before any consumption
    float4 L0 = ((const float4*)rp0)[0];
    float4 L1 = ((const float4*)rp0)[1];
    float4 L2 = ((const float4*)rp0)[2];
    float4 L3 = ((const float4*)rp1)[0];
    float4 L4 = ((const float4*)rp1)[1];
    float4 L5 = ((const float4*)rp1)[2];
    float px[2][12] = {{L0.x,L0.y,L0.z,L0.w,L1.x,L1.y,L1.z,L1.w,L2.x,L2.y,L2.z,L2.w},
                       {L3.x,L3.y,L3.z,L3.w,L4.x,L4.y,L4.z,L4.w,L5.x,L5.y,L5.z,L5.w}};
    float yv[2][4], cbv[2][4], crv[2][4];
    #pragma unroll
    for (int rr = 0; rr < 2; ++rr) {
      #pragma unroll
      for (int p = 0; p < 4; ++p) {
        float r = to255(px[rr][3*p+0]);
        float g = to255(px[rr][3*p+1]);
        float b = to255(px[rr][3*p+2]);
        float y  =  0.299f*r + 0.587f*g + 0.114f*b;
        float cb = -0.168736f*r - 0.331264f*g + 0.5f*b + 128.0f;
        float cr =  0.5f*r - 0.418688f*g - 0.081312f*b + 128.0f;
        yv[rr][p]  = y - 128.0f;
        cbv[rr][p] = cb;
        crv[rr][p] = cr;
      }
    }
    *(float4*)&A[(2*pr+0)*36 + 4*pc] = make_float4(yv[0][0],yv[0][1],yv[0][2],yv[0][3]);
    *(float4*)&A[(2*pr+1)*36 + 4*pc] = make_float4(yv[1][0],yv[1][1],yv[1][2],yv[1][3]);
    float cb0 = ((cbv[0][0]+cbv[0][1]) + (cbv[1][0]+cbv[1][1]))*0.25f - 128.0f;
    float cb1 = ((cbv[0][2]+cbv[0][3]) + (cbv[1][2]+cbv[1][3]))*0.25f - 128.0f;
    float cr0 = ((crv[0][0]+crv[0][1]) + (crv[1][0]+crv[1][1]))*0.25f - 128.0f;
    float cr1 = ((crv[0][2]+crv[0][3]) + (crv[1][2]+crv[1][3]))*0.25f - 128.0f;
    *(float2*)&A[576 + pr*20 + 2*pc] = make_float2(cb0, cb1);
    *(float2*)&A[736 + pr*20 + 2*pc] = make_float2(cr0, cr1);
  }
  // no barrier: same-wave DS ordering guarantees visibility

  // Plane address for (block tb, row idx) — blocks 0..7 luma (2 rows x 4
  // cols of 8x8), 8..9 Cb, 10..11 Cr.
  auto planeAddr = [](int tb, int i) -> int {
    if (tb < 8)  return ((tb >> 2)*8 + i)*36 + (tb & 3)*8;
    if (tb < 10) return 576 + i*20 + (tb - 8)*8;
    return 736 + i*20 + (tb - 10)*8;
  };

  // ---------------- pass A: row DCT, A planes -> B scratch (96 tasks)
  #pragma unroll
  for (int iter = 0; iter < 2; ++iter) {
    const int task = iter*64 + l;
    if (task < 96) {
      const int tb = task >> 3, i = task & 7;
      const float* src = A + planeAddr(tb, i);
      float xr[8], u[8];
      *(float4*)&xr[0] = *(const float4*)&src[0];
      *(float4*)&xr[4] = *(const float4*)&src[4];
      dct8(xr, u);
      *(float4*)&B[tb*68 + i*8 + 0] = make_float4(u[0],u[1],u[2],u[3]);
      *(float4*)&B[tb*68 + i*8 + 4] = make_float4(u[4],u[5],u[6],u[7]);
    }
  }

  // ---------------- pass B+C: col DCT + quant + col IDCT, B -> A scratch
  #pragma unroll
  for (int iter = 0; iter < 2; ++iter) {
    const int task = iter*64 + l;
    if (task < 96) {
      const int tb = task >> 3, kk = task & 7;
      float s[8], u[8], v[8];
      #pragma unroll
      for (int i = 0; i < 8; ++i) s[i] = B[tb*68 + i*8 + kk];
      dct8(s, u);
      if (tb < 8) {
        #pragma unroll
        for (int m = 0; m < 8; ++m) u[m] = quant_rt(u[m], QLp.v[m][kk]);
      } else {
        #pragma unroll
        for (int m = 0; m < 8; ++m) u[m] = quant_rt(u[m], QCp.v[m][kk]);
      }
      idct8(u, v);
      *(float4*)&A[tb*68 + kk*8 + 0] = make_float4(v[0],v[1],v[2],v[3]);
      *(float4*)&A[tb*68 + kk*8 + 4] = make_float4(v[4],v[5],v[6],v[7]);
    }
  }

  // ---------------- pass D: row IDCT, A scratch -> B rec planes
  #pragma unroll
  for (int iter = 0; iter < 2; ++iter) {
    const int task = iter*64 + l;
    if (task < 96) {
      const int tb = task >> 3, j = task & 7;
      float wv[8], z[8];
      #pragma unroll
      for (int m = 0; m < 8; ++m) wv[m] = A[tb*68 + m*8 + j];
      idct8(wv, z);
      float* dst = B + planeAddr(tb, j);
      *(float4*)&dst[0] = make_float4(z[0],z[1],z[2],z[3]);
      *(float4*)&dst[4] = make_float4(z[4],z[5],z[6],z[7]);
    }
  }

  // ---------------- epilogue: upsample, YCbCr->RGB, round/clip, *(1/255)
  {
    const float c255 = (float)(1.0 / 255.0);  // <=1 ulp vs true div
    float y0[4], y1[4];
    *(float4*)y0 = *(const float4*)&B[(2*pr+0)*36 + 4*pc];
    *(float4*)y1 = *(const float4*)&B[(2*pr+1)*36 + 4*pc];
    float2 cbp2 = *(const float2*)&B[576 + pr*20 + 2*pc];
    float2 crp2 = *(const float2*)&B[736 + pr*20 + 2*pc];
    float cbq[2] = {cbp2.x, cbp2.y};
    float crq[2] = {crp2.x, crp2.y};
    #pragma unroll
    for (int rr = 0; rr < 2; ++rr) {
      float ov[12];
      #pragma unroll
      for (int p = 0; p < 4; ++p) {
        float y2  = (rr ? y1[p] : y0[p]) + 128.0f;
        float cb2 = cbq[p>>1] + 128.0f;
        float cr2 = crq[p>>1] + 128.0f;
        float r2 = y2 + 1.402f*(cr2 - 128.0f);
        float g2 = y2 - 0.344136f*(cb2 - 128.0f) - 0.714136f*(cr2 - 128.0f);
        float b2 = y2 + 1.772f*(cb2 - 128.0f);
        ov[3*p+0] = rintf(fminf(fmaxf(r2, 0.0f), 255.0f)) * c255;
        ov[3*p+1] = rintf(fminf(fmaxf(g2, 0.0f), 255.0f)) * c255;
        ov[3*p+2] = rintf(fminf(fmaxf(b2, 0.0f), 255.0f)) * c255;
      }
      const size_t grow = (size_t)img * 512 + (size_t)(ty*16 + 2*pr + rr);
      float* op = out + (grow*512 + colbase)*3;
      ((float4*)op)[0] = make_float4(ov[0],ov[1],ov[2],ov[3]);
      ((float4*)op)[1] = make_float4(ov[4],ov[5],ov[6],ov[7]);
      ((float4*)op)[2] = make_float4(ov[8],ov[9],ov[10],ov[11]);
    }
  }
}

extern "C" void kernel_launch(void* const* d_in, const int* in_sizes, int n_in,
                              void* d_out, int out_size, void* d_ws, size_t ws_size,
                              hipStream_t stream) {
  (void)in_sizes; (void)n_in; (void)d_ws; (void)ws_size; (void)out_size;
  const float* x = (const float*)d_in[0];
  float* out = (float*)d_out;
  dim3 grid(8, 32, 32);   // W/64, H/16, B
  jpeg_rt<<<grid, dim3(128), 0, stream>>>(x, out);
}

// Round 5
// 186.221 us; speedup vs baseline: 1.0145x; 1.0145x over previous
//
#include <hip/hip_runtime.h>
#include <cstddef>

// DCT-II matrix (float32 cast of numpy's float64 values)
static constexpr float D8[8][8] = {
  { 0.35355339059327373f, 0.35355339059327373f, 0.35355339059327373f, 0.35355339059327373f,
    0.35355339059327373f, 0.35355339059327373f, 0.35355339059327373f, 0.35355339059327373f},
  { 0.4903926402016152f,  0.4157348061512726f,  0.27778511650980114f, 0.09754516100806417f,
   -0.09754516100806417f,-0.27778511650980114f,-0.4157348061512726f, -0.4903926402016152f},
  { 0.46193976625564337f, 0.19134171618254492f,-0.19134171618254492f,-0.46193976625564337f,
   -0.46193976625564337f,-0.19134171618254492f, 0.19134171618254492f, 0.46193976625564337f},
  { 0.4157348061512726f, -0.09754516100806417f,-0.4903926402016152f, -0.27778511650980114f,
    0.27778511650980114f, 0.4903926402016152f,  0.09754516100806417f,-0.4157348061512726f},
  { 0.35355339059327373f,-0.35355339059327373f,-0.35355339059327373f, 0.35355339059327373f,
    0.35355339059327373f,-0.35355339059327373f,-0.35355339059327373f, 0.35355339059327373f},
  { 0.27778511650980114f,-0.4903926402016152f,  0.09754516100806417f, 0.4157348061512726f,
   -0.4157348061512726f, -0.09754516100806417f, 0.4903926402016152f, -0.27778511650980114f},
  { 0.19134171618254492f,-0.46193976625564337f, 0.46193976625564337f,-0.19134171618254492f,
   -0.19134171618254492f, 0.46193976625564337f,-0.46193976625564337f, 0.19134171618254492f},
  { 0.09754516100806417f,-0.27778511650980114f, 0.4157348061512726f, -0.4903926402016152f,
    0.4903926402016152f, -0.4157348061512726f,  0.27778511650980114f,-0.09754516100806417f},
};

// Quality-95 quant tables: q = clamp(floor((base*10+50)/100), 1, 255)
static constexpr float QLt[8][8] = {
  {2,1,1,2,2,4,5,6},
  {1,1,1,2,3,6,6,6},
  {1,1,2,2,4,6,7,6},
  {1,2,2,3,5,9,8,6},
  {2,2,4,6,7,11,10,8},
  {2,4,6,6,8,10,11,9},
  {5,6,8,9,10,12,12,10},
  {7,9,10,10,11,10,10,10},
};
static constexpr float QCt[8][8] = {
  {2,2,2,5,10,10,10,10},
  {2,2,3,7,10,10,10,10},
  {2,3,6,10,10,10,10,10},
  {5,7,10,10,10,10,10,10},
  {10,10,10,10,10,10,10,10},
  {10,10,10,10,10,10,10,10},
  {10,10,10,10,10,10,10,10},
  {10,10,10,10,10,10,10,10},
};

// Quant entries: (RN_f64(1/q), q). 16B so each is one dwordx4 load (L1-hot).
struct QE { double r; float q; float pad; };
struct QTabE { QE v[8][8]; };
static constexpr QTabE mkqe(const float (&b)[8][8]) {
  QTabE t{};
  for (int i = 0; i < 8; ++i)
    for (int j = 0; j < 8; ++j)
      t.v[i][j] = QE{1.0 / (double)b[i][j], b[i][j], 0.0f};
  return t;
}
static constexpr QTabE QLe = mkqe(QLt);
static constexpr QTabE QCe = mkqe(QCt);

__device__ __forceinline__ void dct8(const float x[8], float u[8]) {
  #pragma unroll
  for (int k = 0; k < 8; ++k) {
    float a = D8[k][0] * x[0];
    #pragma unroll
    for (int j = 1; j < 8; ++j) a += D8[k][j] * x[j];
    u[k] = a;
  }
}
__device__ __forceinline__ void idct8(const float x[8], float u[8]) {
  #pragma unroll
  for (int j = 0; j < 8; ++j) {
    float a = x[0] * D8[0][j];
    #pragma unroll
    for (int m = 1; m < 8; ++m) a += x[m] * D8[m][j];
    u[j] = a;
  }
}

// Branchless bit-exact RN_f32(x / c255), c255 = RN_f32(1/255) = 8421505*2^-31:
// f64 multiply by RN_f64(1/c255) has abs error <= 2^-44 while the exact
// quotient is >= ~2^-39 from any f32 rounding midpoint (odd-mantissa proof),
// so rounding to f32 reproduces the IEEE f32 division bit-for-bit.
__device__ __forceinline__ float to255(float x) {
  constexpr double R = 1.0 / (double)(1.0f / 255.0f);
  float q = (float)((double)x * R);
  return fminf(fmaxf(floorf(q), 0.0f), 255.0f);
}

// Branchless bit-exact round(RN_f32(u/q)) for integer q in [1,12]: same
// f64-reciprocal argument (margin 2^-28 rel >> 2^-52 rel error). rintf =
// round-half-even = jnp.round.
__device__ __forceinline__ float quant_rt(float u, const QE& e) {
  float t = (float)((double)u * e.r);
  return rintf(t) * e.q;
}

// Wave-autonomous, barrier-free: each wave64 owns a 16x32 strip (8 luma +
// 2 Cb + 2 Cr 8x8 blocks) end-to-end in a private 896-float LDS slice.
// All DCT passes run IN-PLACE: within a wave64, each pass's ds_reads
// lockstep-precede its ds_writes (in-order DS pipe), so planes and scratch
// share one region. Layout:
//   planes : Y[16][36]@0 (576) | Cb[8][20]@576 | Cr[8][20]@736   (896 fl)
//   scratch: S[12][68]@0..816  (aliases planes between the passes)
// Aliasing audit (t0 = tasks 0..63 luma, t1 = tasks 64..95 chroma, l<32):
//   pass A : t0 reads Y(0..575) then writes S[0..7](0..543)  [lockstep ok]
//            t1 reads chroma(576..895) -- disjoint from t0 writes; t1
//            writes S[8..11](544..815) after its own reads    [ok]
//   pass BC: per-task in-place transpose, reads precede writes [ok]
//   pass D : t0 writes Y(0..575) OVERLAP t1 reads S[8](544..611) -> t1's
//            8 reads are STAGED before t0's writes             [fixed]
// Block = 128 thr = 2 waves = 7168 B LDS -> LDS cap 32 waves/CU.
__global__ __launch_bounds__(128, 8) void jpeg_rt(const float* __restrict__ in,
                                                  float* __restrict__ out)
{
  __shared__ __align__(16) float LDSB[2 * 896];

  const int t   = threadIdx.x;
  const int w   = t >> 6;       // wave 0..1
  const int l   = t & 63;       // lane
  const int tx  = blockIdx.x;   // 0..7  (64-col band)
  const int ty  = blockIdx.y;   // 0..31 (16-row band)
  const int img = blockIdx.z;   // 0..31

  float* P = LDSB + w * 896;

  const int pr = l >> 3;        // 0..7: pixel rows 2pr,2pr+1
  const int pc = l & 7;         // 0..7: pixel cols 4pc..4pc+3 (in strip)
  const int colbase = tx*64 + w*32 + 4*pc;

  // ---------------- stage 1: load 2x4 patch, color convert -> planes
  {
    const size_t r0 = (size_t)img * 512 + (size_t)(ty*16 + 2*pr);
    const float* rp0 = in + (r0*512 + colbase)*3;
    const float* rp1 = rp0 + 512*3;
    float4 L0 = ((const float4*)rp0)[0];
    float4 L1 = ((const float4*)rp0)[1];
    float4 L2 = ((const float4*)rp0)[2];
    float4 L3 = ((const float4*)rp1)[0];
    float4 L4 = ((const float4*)rp1)[1];
    float4 L5 = ((const float4*)rp1)[2];
    float px[2][12] = {{L0.x,L0.y,L0.z,L0.w,L1.x,L1.y,L1.z,L1.w,L2.x,L2.y,L2.z,L2.w},
                       {L3.x,L3.y,L3.z,L3.w,L4.x,L4.y,L4.z,L4.w,L5.x,L5.y,L5.z,L5.w}};
    float yv[2][4], cbv[2][4], crv[2][4];
    #pragma unroll
    for (int rr = 0; rr < 2; ++rr) {
      #pragma unroll
      for (int p = 0; p < 4; ++p) {
        float r = to255(px[rr][3*p+0]);
        float g = to255(px[rr][3*p+1]);
        float b = to255(px[rr][3*p+2]);
        float y  =  0.299f*r + 0.587f*g + 0.114f*b;
        float cb = -0.168736f*r - 0.331264f*g + 0.5f*b + 128.0f;
        float cr =  0.5f*r - 0.418688f*g - 0.081312f*b + 128.0f;
        yv[rr][p]  = y - 128.0f;
        cbv[rr][p] = cb;
        crv[rr][p] = cr;
      }
    }
    *(float4*)&P[(2*pr+0)*36 + 4*pc] = make_float4(yv[0][0],yv[0][1],yv[0][2],yv[0][3]);
    *(float4*)&P[(2*pr+1)*36 + 4*pc] = make_float4(yv[1][0],yv[1][1],yv[1][2],yv[1][3]);
    float cb0 = ((cbv[0][0]+cbv[0][1]) + (cbv[1][0]+cbv[1][1]))*0.25f - 128.0f;
    float cb1 = ((cbv[0][2]+cbv[0][3]) + (cbv[1][2]+cbv[1][3]))*0.25f - 128.0f;
    float cr0 = ((crv[0][0]+crv[0][1]) + (crv[1][0]+crv[1][1]))*0.25f - 128.0f;
    float cr1 = ((crv[0][2]+crv[0][3]) + (crv[1][2]+crv[1][3]))*0.25f - 128.0f;
    *(float2*)&P[576 + pr*20 + 2*pc] = make_float2(cb0, cb1);
    *(float2*)&P[736 + pr*20 + 2*pc] = make_float2(cr0, cr1);
  }

  // Plane address for (block tb, row i): tb 0..7 luma (2x4 grid), 8..9 Cb,
  // 10..11 Cr.
  auto planeAddr = [](int tb, int i) -> int {
    if (tb < 8)  return ((tb >> 2)*8 + i)*36 + (tb & 3)*8;
    if (tb < 10) return 576 + i*20 + (tb - 8)*8;
    return 736 + i*20 + (tb - 10)*8;
  };

  const int tb0 = l >> 3;        // luma block (iter 0)
  const int tb1 = 8 + (l >> 3);  // chroma block (iter 1, l < 32)
  const int ri  = l & 7;         // row / column index within block

  // ---------------- pass A: row DCT, planes -> S (in place)
  {
    float xr[8], u[8];
    const float* src = P + planeAddr(tb0, ri);
    *(float4*)&xr[0] = *(const float4*)&src[0];
    *(float4*)&xr[4] = *(const float4*)&src[4];
    dct8(xr, u);
    *(float4*)&P[tb0*68 + ri*8 + 0] = make_float4(u[0],u[1],u[2],u[3]);
    *(float4*)&P[tb0*68 + ri*8 + 4] = make_float4(u[4],u[5],u[6],u[7]);
    if (l < 32) {
      const float* src1 = P + planeAddr(tb1, ri);
      *(float4*)&xr[0] = *(const float4*)&src1[0];
      *(float4*)&xr[4] = *(const float4*)&src1[4];
      dct8(xr, u);
      *(float4*)&P[tb1*68 + ri*8 + 0] = make_float4(u[0],u[1],u[2],u[3]);
      *(float4*)&P[tb1*68 + ri*8 + 4] = make_float4(u[4],u[5],u[6],u[7]);
    }
  }

  // ---------------- pass B+C: col DCT + quant + col IDCT, S -> S (in place)
  {
    float s[8], u[8], v[8];
    #pragma unroll
    for (int i = 0; i < 8; ++i) s[i] = P[tb0*68 + i*8 + ri];
    dct8(s, u);
    #pragma unroll
    for (int m = 0; m < 8; ++m) u[m] = quant_rt(u[m], QLe.v[m][ri]);
    idct8(u, v);
    *(float4*)&P[tb0*68 + ri*8 + 0] = make_float4(v[0],v[1],v[2],v[3]);
    *(float4*)&P[tb0*68 + ri*8 + 4] = make_float4(v[4],v[5],v[6],v[7]);
    if (l < 32) {
      #pragma unroll
      for (int i = 0; i < 8; ++i) s[i] = P[tb1*68 + i*8 + ri];
      dct8(s, u);
      #pragma unroll
      for (int m = 0; m < 8; ++m) u[m] = quant_rt(u[m], QCe.v[m][ri]);
      idct8(u, v);
      *(float4*)&P[tb1*68 + ri*8 + 0] = make_float4(v[0],v[1],v[2],v[3]);
      *(float4*)&P[tb1*68 + ri*8 + 4] = make_float4(v[4],v[5],v[6],v[7]);
    }
  }

  // ---------------- pass D: row IDCT, S -> planes (in place; t1 reads staged
  // BEFORE t0's plane writes, which overlap S[8])
  {
    float w0[8], w1[8], z[8];
    #pragma unroll
    for (int m = 0; m < 8; ++m) w0[m] = P[tb0*68 + m*8 + ri];
    if (l < 32) {
      #pragma unroll
      for (int m = 0; m < 8; ++m) w1[m] = P[tb1*68 + m*8 + ri];
    }
    idct8(w0, z);
    float* dst = P + planeAddr(tb0, ri);
    *(float4*)&dst[0] = make_float4(z[0],z[1],z[2],z[3]);
    *(float4*)&dst[4] = make_float4(z[4],z[5],z[6],z[7]);
    if (l < 32) {
      idct8(w1, z);
      float* dst1 = P + planeAddr(tb1, ri);
      *(float4*)&dst1[0] = make_float4(z[0],z[1],z[2],z[3]);
      *(float4*)&dst1[4] = make_float4(z[4],z[5],z[6],z[7]);
    }
  }

  // ---------------- epilogue: upsample, YCbCr->RGB, round/clip, *(1/255)
  {
    const float c255 = (float)(1.0 / 255.0);  // <=1 ulp vs true div
    float y0[4], y1[4];
    *(float4*)y0 = *(const float4*)&P[(2*pr+0)*36 + 4*pc];
    *(float4*)y1 = *(const float4*)&P[(2*pr+1)*36 + 4*pc];
    float2 cbp2 = *(const float2*)&P[576 + pr*20 + 2*pc];
    float2 crp2 = *(const float2*)&P[736 + pr*20 + 2*pc];
    float cbq[2] = {cbp2.x, cbp2.y};
    float crq[2] = {crp2.x, crp2.y};
    #pragma unroll
    for (int rr = 0; rr < 2; ++rr) {
      float ov[12];
      #pragma unroll
      for (int p = 0; p < 4; ++p) {
        float y2  = (rr ? y1[p] : y0[p]) + 128.0f;
        float cb2 = cbq[p>>1] + 128.0f;
        float cr2 = crq[p>>1] + 128.0f;
        float r2 = y2 + 1.402f*(cr2 - 128.0f);
        float g2 = y2 - 0.344136f*(cb2 - 128.0f) - 0.714136f*(cr2 - 128.0f);
        float b2 = y2 + 1.772f*(cb2 - 128.0f);
        ov[3*p+0] = rintf(fminf(fmaxf(r2, 0.0f), 255.0f)) * c255;
        ov[3*p+1] = rintf(fminf(fmaxf(g2, 0.0f), 255.0f)) * c255;
        ov[3*p+2] = rintf(fminf(fmaxf(b2, 0.0f), 255.0f)) * c255;
      }
      const size_t grow = (size_t)img * 512 + (size_t)(ty*16 + 2*pr + rr);
      float* op = out + (grow*512 + colbase)*3;
      ((float4*)op)[0] = make_float4(ov[0],ov[1],ov[2],ov[3]);
      ((float4*)op)[1] = make_float4(ov[4],ov[5],ov[6],ov[7]);
      ((float4*)op)[2] = make_float4(ov[8],ov[9],ov[10],ov[11]);
    }
  }
}

extern "C" void kernel_launch(void* const* d_in, const int* in_sizes, int n_in,
                              void* d_out, int out_size, void* d_ws, size_t ws_size,
                              hipStream_t stream) {
  (void)in_sizes; (void)n_in; (void)d_ws; (void)ws_size; (void)out_size;
  const float* x = (const float*)d_in[0];
  float* out = (float*)d_out;
  dim3 grid(8, 32, 32);   // W/64, H/16, B
  jpeg_rt<<<grid, dim3(128), 0, stream>>>(x, out);
}